// Round 2
// baseline (1419.905 us; speedup 1.0000x reference)
//
#include <hip/hip_runtime.h>

// LinearAttention: B=4, T=8192, D=512, H=8, DH=64, M=B*T=32768
// prep (W->bf16 pre-swizzled) -> proj(q,k,v) -> ctx/ksum (MFMA) -> numdiv -> out
//
// GEMM geometry (proj/out): BM=128, BN=512 (full width, X read once), BK=32.
// LDS rows padded to 80 B (2-way-free bank access, 16B-aligned v8s frags).
// B-tiles stream via global_load_lds(16B) from a prepacked pad-80 image in ws.
// Epilogue uses operand-swapped MFMA: mfma(Bfrag, Afrag) -> lane holds 4
// consecutive output columns -> packed uint2 (bf16) / float4 (f32) stores.

typedef float v4f __attribute__((ext_vector_type(4)));
typedef short v8s __attribute__((ext_vector_type(8)));

typedef __attribute__((address_space(3))) unsigned int as3_u32;
typedef __attribute__((address_space(1))) unsigned int as1_u32;

__device__ __forceinline__ void glds16(const void* g, void* l) {
  __builtin_amdgcn_global_load_lds((const as1_u32*)g, (as3_u32*)l, 16, 0, 0);
}

__device__ __forceinline__ ushort f2bf(float f) {
  unsigned u = __float_as_uint(f);
  u += 0x7FFFu + ((u >> 16) & 1u);  // RNE
  return (ushort)(u >> 16);
}
__device__ __forceinline__ float bf2f(ushort h) {
  return __uint_as_float(((unsigned)h) << 16);
}
__device__ __forceinline__ unsigned pk2(float a, float b) {
  return (unsigned)f2bf(a) | ((unsigned)f2bf(b) << 16);
}

// ---------------- prep: W f32 -> bf16, pad-80 per-kstep image ---------------
// Wsw[m] block: for kstep ks (0..15): 40960 B: byte(n,kb,r) = n*80 + kb*16 + r*2
//   holds bf16( W[n][ks*32 + kb*8 + r] ).  m in {q,k,v,o}.
__global__ __launch_bounds__(256) void prep_kernel(
    const float* __restrict__ Wq, const float* __restrict__ Wk,
    const float* __restrict__ Wv, const float* __restrict__ Wo,
    char* __restrict__ Wsw) {
  int s = blockIdx.x * 256 + threadIdx.x;  // 131072 total
  int m = s >> 15;
  int r = s & 32767;
  int n = r >> 6;
  int ks = (r >> 2) & 15;
  int kb = r & 3;
  const float* W = (m == 0) ? Wq : (m == 1) ? Wk : (m == 2) ? Wv : Wo;
  const float* src = W + (size_t)n * 512 + ks * 32 + kb * 8;
  v4f a = *reinterpret_cast<const v4f*>(src);
  v4f c = *reinterpret_cast<const v4f*>(src + 4);
  uint4 hv = make_uint4(pk2(a[0], a[1]), pk2(a[2], a[3]), pk2(c[0], c[1]), pk2(c[2], c[3]));
  *reinterpret_cast<uint4*>(Wsw + (size_t)m * 655360 + ks * 40960 + n * 80 + kb * 16) = hv;
}

// ---------------- projection GEMM: Y = act(X @ W^T + b) -> bf16 -------------
// grid (256 m-blocks, 3 inputs), 512 threads = 8 waves (2M x 4N), wave 64x128
__global__ __launch_bounds__(512, 6) void proj_kernel(
    const float* __restrict__ X0, const float* __restrict__ X1, const float* __restrict__ X2,
    const char* __restrict__ WswBase,
    const float* __restrict__ Bb0, const float* __restrict__ Bb1, const float* __restrict__ Bb2,
    ushort* __restrict__ Y0, ushort* __restrict__ Y1, ushort* __restrict__ Y2) {
  __shared__ char As[128 * 80];  // 10240
  __shared__ char Bs[512 * 80];  // 40960
  const int z = blockIdx.y;
  const float* __restrict__ X  = (z == 0) ? X0  : (z == 1) ? X1  : X2;
  const float* __restrict__ Bb = (z == 0) ? Bb0 : (z == 1) ? Bb1 : Bb2;
  ushort* __restrict__ Y       = (z == 0) ? Y0  : (z == 1) ? Y1  : Y2;
  const char* __restrict__ Wsw = WswBase + (size_t)z * 655360;
  const bool do_elu = (z < 2);

  const int tid = threadIdx.x;
  const int lane = tid & 63;
  const int wv = tid >> 6;
  const int wr = wv >> 2, wc = wv & 3;
  const int m0 = blockIdx.x * 128;

  const int arow = tid >> 2;
  const int ac4 = (tid & 3) << 2;
  const float* xrow = X + (size_t)(m0 + arow) * 512 + ac4;

  const v4f vzero = {0.f, 0.f, 0.f, 0.f};
  v4f acc[4][8];
#pragma unroll
  for (int i = 0; i < 4; ++i)
#pragma unroll
    for (int j = 0; j < 8; ++j) acc[i][j] = vzero;

  for (int ks = 0; ks < 16; ++ks) {
    const int k0 = ks << 5;
    __syncthreads();
    // B tile: async DMA, linear (source image is pre-padded/packed)
    {
      const char* wsrc = Wsw + ks * 40960 + wv * 1024 + lane * 16;
      char* bdst = Bs + wv * 1024;
#pragma unroll
      for (int i = 0; i < 5; ++i) glds16(wsrc + i * 8192, bdst + i * 8192);
    }
    // A tile: reg-staged f32 -> bf16
#pragma unroll
    for (int j = 0; j < 2; ++j) {
      v4f xv = *reinterpret_cast<const v4f*>(xrow + k0 + j * 16);
      uint2 hv;
      hv.x = pk2(xv[0], xv[1]);
      hv.y = pk2(xv[2], xv[3]);
      int kk = ac4 + (j << 4);
      *reinterpret_cast<uint2*>(As + arow * 80 + ((kk >> 3) << 4) + ((ac4 & 7) << 1)) = hv;
    }
    __syncthreads();

    const int ko = (lane >> 4) << 4;  // k byte offset
    v8s bfrg[8], afrg[4];
#pragma unroll
    for (int ni = 0; ni < 8; ++ni) {
      int col = (wc << 7) + (ni << 4) + (lane & 15);
      bfrg[ni] = *reinterpret_cast<const v8s*>(Bs + col * 80 + ko);
    }
#pragma unroll
    for (int mi = 0; mi < 4; ++mi) {
      int row = (wr << 6) + (mi << 4) + (lane & 15);
      afrg[mi] = *reinterpret_cast<const v8s*>(As + row * 80 + ko);
    }
#pragma unroll
    for (int mi = 0; mi < 4; ++mi)
#pragma unroll
      for (int ni = 0; ni < 8; ++ni)
        acc[mi][ni] = __builtin_amdgcn_mfma_f32_16x16x32_bf16(bfrg[ni], afrg[mi], acc[mi][ni], 0, 0, 0);
  }

  // swapped epilogue: lane&15 -> Y row, (lane>>4)*4+j -> Y col (4 consecutive)
#pragma unroll
  for (int ni = 0; ni < 8; ++ni) {
    const int col4 = (wc << 7) + (ni << 4) + ((lane >> 4) << 2);
    v4f bb = *reinterpret_cast<const v4f*>(Bb + col4);
#pragma unroll
    for (int mi = 0; mi < 4; ++mi) {
      const int row = m0 + (wr << 6) + (mi << 4) + (lane & 15);
      float v0 = acc[mi][ni][0] + bb[0];
      float v1 = acc[mi][ni][1] + bb[1];
      float v2 = acc[mi][ni][2] + bb[2];
      float v3 = acc[mi][ni][3] + bb[3];
      if (do_elu) {
        v0 = (v0 > 0.f) ? (v0 + 1.f) : __expf(v0);
        v1 = (v1 > 0.f) ? (v1 + 1.f) : __expf(v1);
        v2 = (v2 > 0.f) ? (v2 + 1.f) : __expf(v2);
        v3 = (v3 > 0.f) ? (v3 + 1.f) : __expf(v3);
      }
      uint2 o;
      o.x = pk2(v0, v1);
      o.y = pk2(v2, v3);
      *reinterpret_cast<uint2*>(Y + (size_t)row * 512 + col4) = o;
    }
  }
}

// ---------------- ctx[bh][c][d] = sum_t kh*vh ; ksum[bh][c]  (MFMA) ---------
// grid (8 chunks x 32 bh), 256 threads = 4 waves; K-split over t; LDS-reduce;
// wave0 atomicAdds into zeroed ws.
__global__ __launch_bounds__(256) void ctx_kernel(
    const ushort* __restrict__ KH, const ushort* __restrict__ VH,
    float* __restrict__ CTX, float* __restrict__ KSUM) {
  __shared__ char sm[34816];  // klT[64][136us] + vlT[64][136us]; reused as 2x16KB f32
  __shared__ float ksp[256];
  ushort* klT = (ushort*)sm;            // row stride 272 B
  ushort* vlT = (ushort*)(sm + 17408);
  float* red0 = (float*)sm;
  float* red1 = (float*)(sm + 16384);

  const int tid = threadIdx.x;
  const int lane = tid & 63;
  const int wv = tid >> 6;
  const int bh = blockIdx.y;
  const int b = bh >> 3, h = bh & 7;
  const int tbase = blockIdx.x << 10;

  const v4f vzero = {0.f, 0.f, 0.f, 0.f};
  v4f acc[4][4];
#pragma unroll
  for (int i = 0; i < 4; ++i)
#pragma unroll
    for (int j = 0; j < 4; ++j) acc[i][j] = vzero;
  float ks = 0.f;

  const int c8 = (tid & 7) << 3;
  const int tp = (tid >> 3) << 1;  // even t in [0,64)

  for (int it = 0; it < 8; ++it) {
    __syncthreads();
    // stage + transpose 128 t x 64 c of kh and vh
#pragma unroll
    for (int r = 0; r < 2; ++r) {
      int tloc = tp + (r << 6);
      size_t g = ((size_t)(b * 8192 + tbase + (it << 7) + tloc)) * 512 + (h << 6) + c8;
      uint4 ka = *reinterpret_cast<const uint4*>(KH + g);
      uint4 kb = *reinterpret_cast<const uint4*>(KH + g + 512);
      uint4 va = *reinterpret_cast<const uint4*>(VH + g);
      uint4 vb = *reinterpret_cast<const uint4*>(VH + g + 512);
      const ushort* pka = (const ushort*)&ka;
      const ushort* pkb = (const ushort*)&kb;
      const ushort* pva = (const ushort*)&va;
      const ushort* pvb = (const ushort*)&vb;
#pragma unroll
      for (int i = 0; i < 8; ++i) {
        unsigned kw = (unsigned)pka[i] | ((unsigned)pkb[i] << 16);
        unsigned vw = (unsigned)pva[i] | ((unsigned)pvb[i] << 16);
        *reinterpret_cast<unsigned*>((char*)klT + (c8 + i) * 272 + tloc * 2) = kw;
        *reinterpret_cast<unsigned*>((char*)vlT + (c8 + i) * 272 + tloc * 2) = vw;
      }
    }
    __syncthreads();
    // wave wv: t-range [wv*32, +32) of this 128-t tile
    const int tw = wv << 5;
    const int ko = (tw + ((lane >> 4) << 3)) << 1;  // byte offset along t
    v8s af[4], bf_[4];
#pragma unroll
    for (int ci = 0; ci < 4; ++ci)
      af[ci] = *reinterpret_cast<const v8s*>((char*)klT + ((ci << 4) + (lane & 15)) * 272 + ko);
#pragma unroll
    for (int di = 0; di < 4; ++di)
      bf_[di] = *reinterpret_cast<const v8s*>((char*)vlT + ((di << 4) + (lane & 15)) * 272 + ko);
#pragma unroll
    for (int ci = 0; ci < 4; ++ci)
#pragma unroll
      for (int di = 0; di < 4; ++di)
        acc[ci][di] = __builtin_amdgcn_mfma_f32_16x16x32_bf16(af[ci], bf_[di], acc[ci][di], 0, 0, 0);
    // ksum partial: lane sums row c=lane over this wave's t-range
#pragma unroll
    for (int q = 0; q < 4; ++q) {
      v8s kv = *reinterpret_cast<const v8s*>((char*)klT + lane * 272 + ((tw + (q << 3)) << 1));
#pragma unroll
      for (int i = 0; i < 8; ++i) ks += bf2f((ushort)kv[i]);
    }
  }

  // 3-step LDS reduce of the 4 K-split partials (only 2x16KB LDS available)
  __syncthreads();
  if (wv == 2) {
#pragma unroll
    for (int ci = 0; ci < 4; ++ci)
#pragma unroll
      for (int di = 0; di < 4; ++di)
#pragma unroll
        for (int j = 0; j < 4; ++j)
          red0[((ci << 4) + ((lane >> 4) << 2) + j) * 64 + (di << 4) + (lane & 15)] = acc[ci][di][j];
  }
  if (wv == 3) {
#pragma unroll
    for (int ci = 0; ci < 4; ++ci)
#pragma unroll
      for (int di = 0; di < 4; ++di)
#pragma unroll
        for (int j = 0; j < 4; ++j)
          red1[((ci << 4) + ((lane >> 4) << 2) + j) * 64 + (di << 4) + (lane & 15)] = acc[ci][di][j];
  }
  ksp[tid] = ks;
  __syncthreads();
  if (wv == 0) {
#pragma unroll
    for (int ci = 0; ci < 4; ++ci)
#pragma unroll
      for (int di = 0; di < 4; ++di)
#pragma unroll
        for (int j = 0; j < 4; ++j)
          acc[ci][di][j] += red0[((ci << 4) + ((lane >> 4) << 2) + j) * 64 + (di << 4) + (lane & 15)];
  }
  if (wv == 1) {
#pragma unroll
    for (int ci = 0; ci < 4; ++ci)
#pragma unroll
      for (int di = 0; di < 4; ++di)
#pragma unroll
        for (int j = 0; j < 4; ++j)
          acc[ci][di][j] += red1[((ci << 4) + ((lane >> 4) << 2) + j) * 64 + (di << 4) + (lane & 15)];
  }
  __syncthreads();
  if (wv == 1) {
#pragma unroll
    for (int ci = 0; ci < 4; ++ci)
#pragma unroll
      for (int di = 0; di < 4; ++di)
#pragma unroll
        for (int j = 0; j < 4; ++j)
          red0[((ci << 4) + ((lane >> 4) << 2) + j) * 64 + (di << 4) + (lane & 15)] = acc[ci][di][j];
  }
  __syncthreads();
  if (wv == 0) {
#pragma unroll
    for (int ci = 0; ci < 4; ++ci)
#pragma unroll
      for (int di = 0; di < 4; ++di)
#pragma unroll
        for (int j = 0; j < 4; ++j) {
          int c = (ci << 4) + ((lane >> 4) << 2) + j;
          int d = (di << 4) + (lane & 15);
          float val = acc[ci][di][j] + red0[c * 64 + d];
          atomicAdd(&CTX[(bh << 12) + (c << 6) + d], val);
        }
    float ksv = ksp[lane] + ksp[64 + lane] + ksp[128 + lane] + ksp[192 + lane];
    atomicAdd(&KSUM[(bh << 6) + lane], ksv);
  }
}

// ---------------- o = (qh @ ctx) / (qh . ksum) -> bf16 ----------------------
__global__ __launch_bounds__(256) void numdiv_kernel(
    const ushort* __restrict__ QH, const float* __restrict__ CTX,
    const float* __restrict__ KSUM, ushort* __restrict__ O) {
  __shared__ float ctxl[4096];
  __shared__ float ksl[64];
  __shared__ ushort qtl[64 * 138];
  const int tid = threadIdx.x;
  const int bh = blockIdx.y;
  const int b = bh >> 3, h = bh & 7;
  const int t0 = blockIdx.x << 7;

#pragma unroll
  for (int r = 0; r < 4; ++r) {
    int s = tid + (r << 8);
    int row = s >> 4;
    int c4 = (s & 15) << 2;
    *reinterpret_cast<v4f*>(&ctxl[(row << 6) + c4]) =
        *reinterpret_cast<const v4f*>(&CTX[(bh << 12) + (row << 6) + c4]);
  }
  if (tid < 64) ksl[tid] = KSUM[(bh << 6) + tid];
#pragma unroll
  for (int r = 0; r < 4; ++r) {
    int s = tid + (r << 8);
    int trow = s >> 3;
    int cb = (s & 7) << 3;
    uint4 raw = *reinterpret_cast<const uint4*>(
        QH + ((size_t)(b * 8192 + t0 + trow)) * 512 + (h << 6) + cb);
    const ushort* p = reinterpret_cast<const ushort*>(&raw);
#pragma unroll
    for (int i = 0; i < 8; ++i) qtl[(cb + i) * 138 + trow] = p[i];
  }
  __syncthreads();

  const int l = tid & 63;
  const int dw = (tid >> 6) << 4;
  float a0[16], a1[16];
#pragma unroll
  for (int j = 0; j < 16; ++j) { a0[j] = 0.f; a1[j] = 0.f; }
  float den0 = 0.f, den1 = 0.f;

  for (int c = 0; c < 64; ++c) {
    float q0 = bf2f(qtl[c * 138 + l]);
    float q1 = bf2f(qtl[c * 138 + 64 + l]);
    float kv = ksl[c];
    den0 += q0 * kv;
    den1 += q1 * kv;
#pragma unroll
    for (int p4 = 0; p4 < 4; ++p4) {
      v4f cv = *reinterpret_cast<const v4f*>(&ctxl[(c << 6) + dw + (p4 << 2)]);
#pragma unroll
      for (int jj = 0; jj < 4; ++jj) {
        a0[(p4 << 2) + jj] += q0 * cv[jj];
        a1[(p4 << 2) + jj] += q1 * cv[jj];
      }
    }
  }
  float i0 = 1.f / den0, i1 = 1.f / den1;
  {
    size_t ro = ((size_t)(b * 8192 + t0 + l)) * 512 + (h << 6) + dw;
    uint4 w0 = make_uint4(pk2(a0[0] * i0, a0[1] * i0), pk2(a0[2] * i0, a0[3] * i0),
                          pk2(a0[4] * i0, a0[5] * i0), pk2(a0[6] * i0, a0[7] * i0));
    uint4 w1 = make_uint4(pk2(a0[8] * i0, a0[9] * i0), pk2(a0[10] * i0, a0[11] * i0),
                          pk2(a0[12] * i0, a0[13] * i0), pk2(a0[14] * i0, a0[15] * i0));
    *reinterpret_cast<uint4*>(O + ro) = w0;
    *reinterpret_cast<uint4*>(O + ro + 8) = w1;
  }
  {
    size_t ro = ((size_t)(b * 8192 + t0 + 64 + l)) * 512 + (h << 6) + dw;
    uint4 w0 = make_uint4(pk2(a1[0] * i1, a1[1] * i1), pk2(a1[2] * i1, a1[3] * i1),
                          pk2(a1[4] * i1, a1[5] * i1), pk2(a1[6] * i1, a1[7] * i1));
    uint4 w1 = make_uint4(pk2(a1[8] * i1, a1[9] * i1), pk2(a1[10] * i1, a1[11] * i1),
                          pk2(a1[12] * i1, a1[13] * i1), pk2(a1[14] * i1, a1[15] * i1));
    *reinterpret_cast<uint4*>(O + ro) = w0;
    *reinterpret_cast<uint4*>(O + ro + 8) = w1;
  }
}

// ---------------- out = o @ Wo^T + bo -> f32 --------------------------------
__global__ __launch_bounds__(512, 6) void out_kernel(
    const ushort* __restrict__ O, const char* __restrict__ WswO,
    const float* __restrict__ bo, float* __restrict__ OUT) {
  __shared__ char As[128 * 80];
  __shared__ char Bs[512 * 80];
  const int tid = threadIdx.x;
  const int lane = tid & 63;
  const int wv = tid >> 6;
  const int wr = wv >> 2, wc = wv & 3;
  const int m0 = blockIdx.x * 128;

  const int arow = tid >> 2;
  const int ak = tid & 3;

  const v4f vzero = {0.f, 0.f, 0.f, 0.f};
  v4f acc[4][8];
#pragma unroll
  for (int i = 0; i < 4; ++i)
#pragma unroll
    for (int j = 0; j < 8; ++j) acc[i][j] = vzero;

  for (int ks = 0; ks < 16; ++ks) {
    __syncthreads();
    {
      const char* wsrc = WswO + ks * 40960 + wv * 1024 + lane * 16;
      char* bdst = Bs + wv * 1024;
#pragma unroll
      for (int i = 0; i < 5; ++i) glds16(wsrc + i * 8192, bdst + i * 8192);
    }
    {
      uint4 raw = *reinterpret_cast<const uint4*>(O + (size_t)(m0 + arow) * 512 + (ks << 5) + (ak << 3));
      *reinterpret_cast<uint4*>(As + arow * 80 + (ak << 4)) = raw;
    }
    __syncthreads();

    const int ko = (lane >> 4) << 4;
    v8s bfrg[8], afrg[4];
#pragma unroll
    for (int ni = 0; ni < 8; ++ni) {
      int col = (wc << 7) + (ni << 4) + (lane & 15);
      bfrg[ni] = *reinterpret_cast<const v8s*>(Bs + col * 80 + ko);
    }
#pragma unroll
    for (int mi = 0; mi < 4; ++mi) {
      int row = (wr << 6) + (mi << 4) + (lane & 15);
      afrg[mi] = *reinterpret_cast<const v8s*>(As + row * 80 + ko);
    }
#pragma unroll
    for (int mi = 0; mi < 4; ++mi)
#pragma unroll
      for (int ni = 0; ni < 8; ++ni)
        acc[mi][ni] = __builtin_amdgcn_mfma_f32_16x16x32_bf16(bfrg[ni], afrg[mi], acc[mi][ni], 0, 0, 0);
  }

#pragma unroll
  for (int ni = 0; ni < 8; ++ni) {
    const int col4 = (wc << 7) + (ni << 4) + ((lane >> 4) << 2);
    v4f bb = *reinterpret_cast<const v4f*>(bo + col4);
#pragma unroll
    for (int mi = 0; mi < 4; ++mi) {
      const int row = m0 + (wr << 6) + (mi << 4) + (lane & 15);
      v4f st;
      st[0] = acc[mi][ni][0] + bb[0];
      st[1] = acc[mi][ni][1] + bb[1];
      st[2] = acc[mi][ni][2] + bb[2];
      st[3] = acc[mi][ni][3] + bb[3];
      *reinterpret_cast<v4f*>(OUT + (size_t)row * 512 + col4) = st;
    }
  }
}

extern "C" void kernel_launch(void* const* d_in, const int* in_sizes, int n_in,
                              void* d_out, int out_size, void* d_ws, size_t ws_size,
                              hipStream_t stream) {
  const float* q  = (const float*)d_in[0];
  const float* k  = (const float*)d_in[1];
  const float* v  = (const float*)d_in[2];
  const float* Wq = (const float*)d_in[3];
  const float* bq = (const float*)d_in[4];
  const float* Wk = (const float*)d_in[5];
  const float* bk = (const float*)d_in[6];
  const float* Wv = (const float*)d_in[7];
  const float* bv = (const float*)d_in[8];
  const float* Wo = (const float*)d_in[9];
  const float* bo = (const float*)d_in[10];
  float* out = (float*)d_out;

  // ws: qh | kh | vh | ctx(512K) | ksum(8K) | Wsw(2.5M);  o aliases qh (safe:
  // numdiv stages its exact read region to LDS before overwriting it)
  char* ws = (char*)d_ws;
  const size_t SZ = 33554432ull;
  ushort* qh = (ushort*)(ws);
  ushort* kh = (ushort*)(ws + SZ);
  ushort* vh = (ushort*)(ws + 2 * SZ);
  float* ctx  = (float*)(ws + 3 * SZ);
  float* ksum = (float*)(ws + 3 * SZ + 524288);
  char* wsw   = ws + 3 * SZ + 532480;

  hipMemsetAsync(ws + 3 * SZ, 0, 532480, stream);
  prep_kernel<<<512, 256, 0, stream>>>(Wq, Wk, Wv, Wo, wsw);
  proj_kernel<<<dim3(256, 3), 512, 0, stream>>>(q, k, v, wsw, bq, bk, bv, qh, kh, vh);
  ctx_kernel<<<dim3(8, 32), 256, 0, stream>>>(kh, vh, ctx, ksum);
  numdiv_kernel<<<dim3(64, 32), 256, 0, stream>>>(qh, ctx, ksum, qh);
  out_kernel<<<dim3(256), 512, 0, stream>>>(qh, wsw + 3 * 655360, bo, out);
}

// Round 3
// 922.019 us; speedup vs baseline: 1.5400x; 1.5400x over previous
//
#include <hip/hip_runtime.h>

// LinearAttention: B=4, T=8192, D=512, H=8, DH=64, M=B*T=32768
// prep (W->bf16 pre-swizzled image) -> proj(q,k,v) -> ctx/ksum (MFMA) -> numdiv -> out
//
// GEMM geometry (proj/out): BM=128, BN=512 (full width, X read ONCE), BK=64.
// LDS: 128B rows, XOR-swizzle off = row*128 + ((kb ^ (row&7))<<4)  (0-conflict, r1-proven).
// B streams via global_load_lds(16B) from a PRE-SWIZZLED global image (linear LDS dst).
// Epilogue: operand-swapped MFMA (mfma(B,A)) -> lane holds 4 consecutive out cols.
// NOTE r2 post-mortem: __launch_bounds__(512,6) forced VGPR=40 -> acc spill -> 4GB
// scratch traffic. Use (512,4): budget 512 VGPR, 2 blocks/CU (LDS-limited anyway).

typedef float v4f __attribute__((ext_vector_type(4)));
typedef short v8s __attribute__((ext_vector_type(8)));

typedef __attribute__((address_space(3))) unsigned int as3_u32;
typedef __attribute__((address_space(1))) unsigned int as1_u32;

__device__ __forceinline__ void glds16(const void* g, void* l) {
  __builtin_amdgcn_global_load_lds((const as1_u32*)g, (as3_u32*)l, 16, 0, 0);
}

__device__ __forceinline__ ushort f2bf(float f) {
  unsigned u = __float_as_uint(f);
  u += 0x7FFFu + ((u >> 16) & 1u);  // RNE
  return (ushort)(u >> 16);
}
__device__ __forceinline__ float bf2f(ushort h) {
  return __uint_as_float(((unsigned)h) << 16);
}
__device__ __forceinline__ unsigned pk2(float a, float b) {
  return (unsigned)f2bf(a) | ((unsigned)f2bf(b) << 16);
}

// ---------------- prep: W f32 -> bf16 pre-swizzled image --------------------
// image[z]: for kstep ks (0..7): 64KB block; byte(col,kb) = col*128 + ((kb^(col&7))<<4)
// content = bf16( W[col][ks*64 + kb*8 .. +8) ).   z in {q,k,v,o}.
__global__ __launch_bounds__(256) void prep_kernel(
    const float* __restrict__ Wq, const float* __restrict__ Wk,
    const float* __restrict__ Wv, const float* __restrict__ Wo,
    char* __restrict__ img) {
  int s = blockIdx.x * 256 + threadIdx.x;  // 131072 total
  int z = s >> 15;
  int r = s & 32767;
  int col = r >> 6;
  int ks = (r >> 3) & 7;
  int kb = r & 7;
  const float* W = (z == 0) ? Wq : (z == 1) ? Wk : (z == 2) ? Wv : Wo;
  const float* src = W + (size_t)col * 512 + ks * 64 + kb * 8;
  v4f a = *reinterpret_cast<const v4f*>(src);
  v4f c = *reinterpret_cast<const v4f*>(src + 4);
  uint4 hv = make_uint4(pk2(a[0], a[1]), pk2(a[2], a[3]), pk2(c[0], c[1]), pk2(c[2], c[3]));
  *reinterpret_cast<uint4*>(img + (size_t)z * 524288 + ks * 65536 + col * 128 +
                            (((kb ^ (col & 7)) << 4))) = hv;
}

// ---------------- projection GEMM: Y = act(X @ W^T + b) -> bf16 -------------
// grid (256 m-blocks, 3 inputs), 512 threads = 8 waves (2M x 4N), wave 64x128
__global__ __launch_bounds__(512, 4) void proj_kernel(
    const float* __restrict__ X0, const float* __restrict__ X1, const float* __restrict__ X2,
    const char* __restrict__ imgBase,
    const float* __restrict__ Bb0, const float* __restrict__ Bb1, const float* __restrict__ Bb2,
    ushort* __restrict__ Y0, ushort* __restrict__ Y1, ushort* __restrict__ Y2) {
  __shared__ char As[128 * 128];  // 16384
  __shared__ char Bs[512 * 128];  // 65536
  const int z = blockIdx.y;
  const float* __restrict__ X  = (z == 0) ? X0  : (z == 1) ? X1  : X2;
  const float* __restrict__ Bb = (z == 0) ? Bb0 : (z == 1) ? Bb1 : Bb2;
  ushort* __restrict__ Y       = (z == 0) ? Y0  : (z == 1) ? Y1  : Y2;
  const char* __restrict__ img = imgBase + (size_t)z * 524288;
  const bool do_elu = (z < 2);

  const int tid = threadIdx.x;
  const int lane = tid & 63;
  const int wv = tid >> 6;
  const int wr = wv >> 2, wc = wv & 3;
  const int m0 = blockIdx.x * 128;

  const v4f vzero = {0.f, 0.f, 0.f, 0.f};
  v4f acc[4][8];
#pragma unroll
  for (int i = 0; i < 4; ++i)
#pragma unroll
    for (int j = 0; j < 8; ++j) acc[i][j] = vzero;

  for (int ks = 0; ks < 8; ++ks) {
    const int k0 = ks << 6;
    __syncthreads();
    // B tile: async DMA, linear dst (global image is pre-swizzled)
    {
      const char* wsrc = img + (ks << 16) + (tid << 4);
      char* bdst = Bs + (wv << 10);  // wave-uniform base; HW adds lane*16
#pragma unroll
      for (int i = 0; i < 8; ++i) glds16(wsrc + i * 8192, bdst + i * 8192);
    }
    // A tile: reg-staged f32 -> bf16, swizzled stores
#pragma unroll
    for (int r = 0; r < 2; ++r) {
      int s = tid + (r << 9);
      int row = s >> 3;
      int kb = s & 7;
      const float* src = X + (size_t)(m0 + row) * 512 + k0 + (kb << 3);
      v4f a = *reinterpret_cast<const v4f*>(src);
      v4f c = *reinterpret_cast<const v4f*>(src + 4);
      uint4 hv = make_uint4(pk2(a[0], a[1]), pk2(a[2], a[3]), pk2(c[0], c[1]), pk2(c[2], c[3]));
      *reinterpret_cast<uint4*>(As + (row << 7) + ((kb ^ (row & 7)) << 4)) = hv;
    }
    __syncthreads();

#pragma unroll
    for (int kk = 0; kk < 2; ++kk) {
      const int kb = (kk << 2) + (lane >> 4);
      v8s bfrg[8], afrg[4];
#pragma unroll
      for (int ni = 0; ni < 8; ++ni) {
        int col = (wc << 7) + (ni << 4) + (lane & 15);
        bfrg[ni] = *reinterpret_cast<const v8s*>(Bs + (col << 7) + ((kb ^ (col & 7)) << 4));
      }
#pragma unroll
      for (int mi = 0; mi < 4; ++mi) {
        int row = (wr << 6) + (mi << 4) + (lane & 15);
        afrg[mi] = *reinterpret_cast<const v8s*>(As + (row << 7) + ((kb ^ (row & 7)) << 4));
      }
#pragma unroll
      for (int mi = 0; mi < 4; ++mi)
#pragma unroll
        for (int ni = 0; ni < 8; ++ni)
          acc[mi][ni] = __builtin_amdgcn_mfma_f32_16x16x32_bf16(bfrg[ni], afrg[mi], acc[mi][ni], 0, 0, 0);
    }
  }

  // swapped epilogue: lane&15 -> Y row, (lane>>4)*4+j -> Y col (4 consecutive)
#pragma unroll
  for (int ni = 0; ni < 8; ++ni) {
    const int col4 = (wc << 7) + (ni << 4) + ((lane >> 4) << 2);
    v4f bb = *reinterpret_cast<const v4f*>(Bb + col4);
#pragma unroll
    for (int mi = 0; mi < 4; ++mi) {
      const int row = m0 + (wr << 6) + (mi << 4) + (lane & 15);
      float v0 = acc[mi][ni][0] + bb[0];
      float v1 = acc[mi][ni][1] + bb[1];
      float v2 = acc[mi][ni][2] + bb[2];
      float v3 = acc[mi][ni][3] + bb[3];
      if (do_elu) {
        v0 = (v0 > 0.f) ? (v0 + 1.f) : __expf(v0);
        v1 = (v1 > 0.f) ? (v1 + 1.f) : __expf(v1);
        v2 = (v2 > 0.f) ? (v2 + 1.f) : __expf(v2);
        v3 = (v3 > 0.f) ? (v3 + 1.f) : __expf(v3);
      }
      uint2 o;
      o.x = pk2(v0, v1);
      o.y = pk2(v2, v3);
      *reinterpret_cast<uint2*>(Y + (size_t)row * 512 + col4) = o;
    }
  }
}

// ---------------- ctx[bh][c][d] = sum_t kh*vh ; ksum[bh][c]  (MFMA) ---------
__global__ __launch_bounds__(256) void ctx_kernel(
    const ushort* __restrict__ KH, const ushort* __restrict__ VH,
    float* __restrict__ CTX, float* __restrict__ KSUM) {
  __shared__ char sm[34816];  // klT[64][136us] + vlT[64][136us]; reused as 2x16KB f32
  __shared__ float ksp[256];
  ushort* klT = (ushort*)sm;            // row stride 272 B
  ushort* vlT = (ushort*)(sm + 17408);
  float* red0 = (float*)sm;
  float* red1 = (float*)(sm + 16384);

  const int tid = threadIdx.x;
  const int lane = tid & 63;
  const int wv = tid >> 6;
  const int bh = blockIdx.y;
  const int b = bh >> 3, h = bh & 7;
  const int tbase = blockIdx.x << 10;

  const v4f vzero = {0.f, 0.f, 0.f, 0.f};
  v4f acc[4][4];
#pragma unroll
  for (int i = 0; i < 4; ++i)
#pragma unroll
    for (int j = 0; j < 4; ++j) acc[i][j] = vzero;
  float ks = 0.f;

  const int c8 = (tid & 7) << 3;
  const int tp = (tid >> 3) << 1;  // even t in [0,64)

  for (int it = 0; it < 8; ++it) {
    __syncthreads();
#pragma unroll
    for (int r = 0; r < 2; ++r) {
      int tloc = tp + (r << 6);
      size_t g = ((size_t)(b * 8192 + tbase + (it << 7) + tloc)) * 512 + (h << 6) + c8;
      uint4 ka = *reinterpret_cast<const uint4*>(KH + g);
      uint4 kb = *reinterpret_cast<const uint4*>(KH + g + 512);
      uint4 va = *reinterpret_cast<const uint4*>(VH + g);
      uint4 vb = *reinterpret_cast<const uint4*>(VH + g + 512);
      const ushort* pka = (const ushort*)&ka;
      const ushort* pkb = (const ushort*)&kb;
      const ushort* pva = (const ushort*)&va;
      const ushort* pvb = (const ushort*)&vb;
#pragma unroll
      for (int i = 0; i < 8; ++i) {
        unsigned kw = (unsigned)pka[i] | ((unsigned)pkb[i] << 16);
        unsigned vw = (unsigned)pva[i] | ((unsigned)pvb[i] << 16);
        *reinterpret_cast<unsigned*>((char*)klT + (c8 + i) * 272 + tloc * 2) = kw;
        *reinterpret_cast<unsigned*>((char*)vlT + (c8 + i) * 272 + tloc * 2) = vw;
      }
    }
    __syncthreads();
    const int tw = wv << 5;
    const int ko = (tw + ((lane >> 4) << 3)) << 1;
    v8s af[4], bf_[4];
#pragma unroll
    for (int ci = 0; ci < 4; ++ci)
      af[ci] = *reinterpret_cast<const v8s*>((char*)klT + ((ci << 4) + (lane & 15)) * 272 + ko);
#pragma unroll
    for (int di = 0; di < 4; ++di)
      bf_[di] = *reinterpret_cast<const v8s*>((char*)vlT + ((di << 4) + (lane & 15)) * 272 + ko);
#pragma unroll
    for (int ci = 0; ci < 4; ++ci)
#pragma unroll
      for (int di = 0; di < 4; ++di)
        acc[ci][di] = __builtin_amdgcn_mfma_f32_16x16x32_bf16(af[ci], bf_[di], acc[ci][di], 0, 0, 0);
#pragma unroll
    for (int q = 0; q < 4; ++q) {
      v8s kv = *reinterpret_cast<const v8s*>((char*)klT + lane * 272 + ((tw + (q << 3)) << 1));
#pragma unroll
      for (int i = 0; i < 8; ++i) ks += bf2f((ushort)kv[i]);
    }
  }

  __syncthreads();
  if (wv == 2) {
#pragma unroll
    for (int ci = 0; ci < 4; ++ci)
#pragma unroll
      for (int di = 0; di < 4; ++di)
#pragma unroll
        for (int j = 0; j < 4; ++j)
          red0[((ci << 4) + ((lane >> 4) << 2) + j) * 64 + (di << 4) + (lane & 15)] = acc[ci][di][j];
  }
  if (wv == 3) {
#pragma unroll
    for (int ci = 0; ci < 4; ++ci)
#pragma unroll
      for (int di = 0; di < 4; ++di)
#pragma unroll
        for (int j = 0; j < 4; ++j)
          red1[((ci << 4) + ((lane >> 4) << 2) + j) * 64 + (di << 4) + (lane & 15)] = acc[ci][di][j];
  }
  ksp[tid] = ks;
  __syncthreads();
  if (wv == 0) {
#pragma unroll
    for (int ci = 0; ci < 4; ++ci)
#pragma unroll
      for (int di = 0; di < 4; ++di)
#pragma unroll
        for (int j = 0; j < 4; ++j)
          acc[ci][di][j] += red0[((ci << 4) + ((lane >> 4) << 2) + j) * 64 + (di << 4) + (lane & 15)];
  }
  if (wv == 1) {
#pragma unroll
    for (int ci = 0; ci < 4; ++ci)
#pragma unroll
      for (int di = 0; di < 4; ++di)
#pragma unroll
        for (int j = 0; j < 4; ++j)
          acc[ci][di][j] += red1[((ci << 4) + ((lane >> 4) << 2) + j) * 64 + (di << 4) + (lane & 15)];
  }
  __syncthreads();
  if (wv == 1) {
#pragma unroll
    for (int ci = 0; ci < 4; ++ci)
#pragma unroll
      for (int di = 0; di < 4; ++di)
#pragma unroll
        for (int j = 0; j < 4; ++j)
          red0[((ci << 4) + ((lane >> 4) << 2) + j) * 64 + (di << 4) + (lane & 15)] = acc[ci][di][j];
  }
  __syncthreads();
  if (wv == 0) {
#pragma unroll
    for (int ci = 0; ci < 4; ++ci)
#pragma unroll
      for (int di = 0; di < 4; ++di)
#pragma unroll
        for (int j = 0; j < 4; ++j) {
          int c = (ci << 4) + ((lane >> 4) << 2) + j;
          int d = (di << 4) + (lane & 15);
          float val = acc[ci][di][j] + red0[c * 64 + d];
          atomicAdd(&CTX[(bh << 12) + (c << 6) + d], val);
        }
    float ksv = ksp[lane] + ksp[64 + lane] + ksp[128 + lane] + ksp[192 + lane];
    atomicAdd(&KSUM[(bh << 6) + lane], ksv);
  }
}

// ---------------- o = (qh @ ctx) / (qh . ksum) -> bf16 ----------------------
__global__ __launch_bounds__(256) void numdiv_kernel(
    const ushort* __restrict__ QH, const float* __restrict__ CTX,
    const float* __restrict__ KSUM, ushort* __restrict__ O) {
  __shared__ float ctxl[4096];
  __shared__ float ksl[64];
  __shared__ ushort qtl[64 * 138];
  const int tid = threadIdx.x;
  const int bh = blockIdx.y;
  const int b = bh >> 3, h = bh & 7;
  const int t0 = blockIdx.x << 7;

#pragma unroll
  for (int r = 0; r < 4; ++r) {
    int s = tid + (r << 8);
    int row = s >> 4;
    int c4 = (s & 15) << 2;
    *reinterpret_cast<v4f*>(&ctxl[(row << 6) + c4]) =
        *reinterpret_cast<const v4f*>(&CTX[(bh << 12) + (row << 6) + c4]);
  }
  if (tid < 64) ksl[tid] = KSUM[(bh << 6) + tid];
#pragma unroll
  for (int r = 0; r < 4; ++r) {
    int s = tid + (r << 8);
    int trow = s >> 3;
    int cb = (s & 7) << 3;
    uint4 raw = *reinterpret_cast<const uint4*>(
        QH + ((size_t)(b * 8192 + t0 + trow)) * 512 + (h << 6) + cb);
    const ushort* p = reinterpret_cast<const ushort*>(&raw);
#pragma unroll
    for (int i = 0; i < 8; ++i) qtl[(cb + i) * 138 + trow] = p[i];
  }
  __syncthreads();

  const int l = tid & 63;
  const int dw = (tid >> 6) << 4;
  float a0[16], a1[16];
#pragma unroll
  for (int j = 0; j < 16; ++j) { a0[j] = 0.f; a1[j] = 0.f; }
  float den0 = 0.f, den1 = 0.f;

  for (int c = 0; c < 64; ++c) {
    float q0 = bf2f(qtl[c * 138 + l]);
    float q1 = bf2f(qtl[c * 138 + 64 + l]);
    float kv = ksl[c];
    den0 += q0 * kv;
    den1 += q1 * kv;
#pragma unroll
    for (int p4 = 0; p4 < 4; ++p4) {
      v4f cv = *reinterpret_cast<const v4f*>(&ctxl[(c << 6) + dw + (p4 << 2)]);
#pragma unroll
      for (int jj = 0; jj < 4; ++jj) {
        a0[(p4 << 2) + jj] += q0 * cv[jj];
        a1[(p4 << 2) + jj] += q1 * cv[jj];
      }
    }
  }
  float i0 = 1.f / den0, i1 = 1.f / den1;
  {
    size_t ro = ((size_t)(b * 8192 + t0 + l)) * 512 + (h << 6) + dw;
    uint4 w0 = make_uint4(pk2(a0[0] * i0, a0[1] * i0), pk2(a0[2] * i0, a0[3] * i0),
                          pk2(a0[4] * i0, a0[5] * i0), pk2(a0[6] * i0, a0[7] * i0));
    uint4 w1 = make_uint4(pk2(a0[8] * i0, a0[9] * i0), pk2(a0[10] * i0, a0[11] * i0),
                          pk2(a0[12] * i0, a0[13] * i0), pk2(a0[14] * i0, a0[15] * i0));
    *reinterpret_cast<uint4*>(O + ro) = w0;
    *reinterpret_cast<uint4*>(O + ro + 8) = w1;
  }
  {
    size_t ro = ((size_t)(b * 8192 + t0 + 64 + l)) * 512 + (h << 6) + dw;
    uint4 w0 = make_uint4(pk2(a1[0] * i1, a1[1] * i1), pk2(a1[2] * i1, a1[3] * i1),
                          pk2(a1[4] * i1, a1[5] * i1), pk2(a1[6] * i1, a1[7] * i1));
    uint4 w1 = make_uint4(pk2(a1[8] * i1, a1[9] * i1), pk2(a1[10] * i1, a1[11] * i1),
                          pk2(a1[12] * i1, a1[13] * i1), pk2(a1[14] * i1, a1[15] * i1));
    *reinterpret_cast<uint4*>(O + ro) = w0;
    *reinterpret_cast<uint4*>(O + ro + 8) = w1;
  }
}

// ---------------- out = o @ Wo^T + bo -> f32 --------------------------------
__global__ __launch_bounds__(512, 4) void out_kernel(
    const ushort* __restrict__ O, const char* __restrict__ imgO,
    const float* __restrict__ bo, float* __restrict__ OUT) {
  __shared__ char As[128 * 128];
  __shared__ char Bs[512 * 128];
  const int tid = threadIdx.x;
  const int lane = tid & 63;
  const int wv = tid >> 6;
  const int wr = wv >> 2, wc = wv & 3;
  const int m0 = blockIdx.x * 128;

  const v4f vzero = {0.f, 0.f, 0.f, 0.f};
  v4f acc[4][8];
#pragma unroll
  for (int i = 0; i < 4; ++i)
#pragma unroll
    for (int j = 0; j < 8; ++j) acc[i][j] = vzero;

  for (int ks = 0; ks < 8; ++ks) {
    const int k0 = ks << 6;
    __syncthreads();
    {
      const char* wsrc = imgO + (ks << 16) + (tid << 4);
      char* bdst = Bs + (wv << 10);
#pragma unroll
      for (int i = 0; i < 8; ++i) glds16(wsrc + i * 8192, bdst + i * 8192);
    }
#pragma unroll
    for (int r = 0; r < 2; ++r) {
      int s = tid + (r << 9);
      int row = s >> 3;
      int kb = s & 7;
      uint4 raw = *reinterpret_cast<const uint4*>(O + (size_t)(m0 + row) * 512 + k0 + (kb << 3));
      *reinterpret_cast<uint4*>(As + (row << 7) + ((kb ^ (row & 7)) << 4)) = raw;
    }
    __syncthreads();

#pragma unroll
    for (int kk = 0; kk < 2; ++kk) {
      const int kb = (kk << 2) + (lane >> 4);
      v8s bfrg[8], afrg[4];
#pragma unroll
      for (int ni = 0; ni < 8; ++ni) {
        int col = (wc << 7) + (ni << 4) + (lane & 15);
        bfrg[ni] = *reinterpret_cast<const v8s*>(Bs + (col << 7) + ((kb ^ (col & 7)) << 4));
      }
#pragma unroll
      for (int mi = 0; mi < 4; ++mi) {
        int row = (wr << 6) + (mi << 4) + (lane & 15);
        afrg[mi] = *reinterpret_cast<const v8s*>(As + (row << 7) + ((kb ^ (row & 7)) << 4));
      }
#pragma unroll
      for (int mi = 0; mi < 4; ++mi)
#pragma unroll
        for (int ni = 0; ni < 8; ++ni)
          acc[mi][ni] = __builtin_amdgcn_mfma_f32_16x16x32_bf16(bfrg[ni], afrg[mi], acc[mi][ni], 0, 0, 0);
    }
  }

#pragma unroll
  for (int ni = 0; ni < 8; ++ni) {
    const int col4 = (wc << 7) + (ni << 4) + ((lane >> 4) << 2);
    v4f bb = *reinterpret_cast<const v4f*>(bo + col4);
#pragma unroll
    for (int mi = 0; mi < 4; ++mi) {
      const int row = m0 + (wr << 6) + (mi << 4) + (lane & 15);
      v4f st;
      st[0] = acc[mi][ni][0] + bb[0];
      st[1] = acc[mi][ni][1] + bb[1];
      st[2] = acc[mi][ni][2] + bb[2];
      st[3] = acc[mi][ni][3] + bb[3];
      *reinterpret_cast<v4f*>(OUT + (size_t)row * 512 + col4) = st;
    }
  }
}

extern "C" void kernel_launch(void* const* d_in, const int* in_sizes, int n_in,
                              void* d_out, int out_size, void* d_ws, size_t ws_size,
                              hipStream_t stream) {
  const float* q  = (const float*)d_in[0];
  const float* k  = (const float*)d_in[1];
  const float* v  = (const float*)d_in[2];
  const float* Wq = (const float*)d_in[3];
  const float* bq = (const float*)d_in[4];
  const float* Wk = (const float*)d_in[5];
  const float* bk = (const float*)d_in[6];
  const float* Wv = (const float*)d_in[7];
  const float* bv = (const float*)d_in[8];
  const float* Wo = (const float*)d_in[9];
  const float* bo = (const float*)d_in[10];
  float* out = (float*)d_out;

  // ws: qh | kh | vh | ctx(512K) | ksum(8K) | Wimg(2M);  o aliases qh (safe:
  // numdiv stages its exact read region to LDS before overwriting it)
  char* ws = (char*)d_ws;
  const size_t SZ = 33554432ull;
  ushort* qh = (ushort*)(ws);
  ushort* kh = (ushort*)(ws + SZ);
  ushort* vh = (ushort*)(ws + 2 * SZ);
  float* ctx  = (float*)(ws + 3 * SZ);
  float* ksum = (float*)(ws + 3 * SZ + 524288);
  char* wimg  = ws + 3 * SZ + 532480;

  hipMemsetAsync(ws + 3 * SZ, 0, 532480, stream);
  prep_kernel<<<512, 256, 0, stream>>>(Wq, Wk, Wv, Wo, wimg);
  proj_kernel<<<dim3(256, 3), 512, 0, stream>>>(q, k, v, wimg, bq, bk, bv, qh, kh, vh);
  ctx_kernel<<<dim3(8, 32), 256, 0, stream>>>(kh, vh, ctx, ksum);
  numdiv_kernel<<<dim3(64, 32), 256, 0, stream>>>(qh, ctx, ksum, qh);
  out_kernel<<<dim3(256), 512, 0, stream>>>(qh, wimg + 3 * 524288, bo, out);
}

// Round 4
// 408.862 us; speedup vs baseline: 3.4728x; 2.2551x over previous
//
#include <hip/hip_runtime.h>

// LinearAttention: B=4, T=8192, D=512, H=8, DH=64, M=B*T=32768
// prep (W->bf16 pre-swizzled image) -> proj(q,k,v) -> ctx/ksum (MFMA) -> numdiv -> out
//
// r3 post-mortem: 64x128 wave tile (acc[4][8]=128 VGPR) + launch_bounds cap
// forced accumulator spill (VGPR=64, 2.4GB scratch traffic). r4 reverts to the
// r1-proven 4-wave 128x128 block (wave tile 64x64, acc[4][4], VGPR~108, zero
// bank conflicts) and keeps the good r2/r3 ideas: prepacked bf16 W image
// streamed via global_load_lds(16B), out_kernel A-tile via global_load_lds with
// swizzle applied to the per-lane GLOBAL source (LDS dst linear), swapped-MFMA
// epilogue for packed stores.
//
// LDS tiles: 128 rows x 64 k bf16, row stride 128B, XOR swizzle
//   byte(row, kb) = row*128 + ((kb ^ (row&7))<<4),  kb = 16B chunk index (0..7).

typedef float v4f __attribute__((ext_vector_type(4)));
typedef short v8s __attribute__((ext_vector_type(8)));

typedef __attribute__((address_space(3))) unsigned int as3_u32;
typedef __attribute__((address_space(1))) unsigned int as1_u32;

__device__ __forceinline__ void glds16(const void* g, void* l) {
  __builtin_amdgcn_global_load_lds((const as1_u32*)g, (as3_u32*)l, 16, 0, 0);
}

__device__ __forceinline__ ushort f2bf(float f) {
  unsigned u = __float_as_uint(f);
  u += 0x7FFFu + ((u >> 16) & 1u);  // RNE
  return (ushort)(u >> 16);
}
__device__ __forceinline__ float bf2f(ushort h) {
  return __uint_as_float(((unsigned)h) << 16);
}
__device__ __forceinline__ unsigned pk2(float a, float b) {
  return (unsigned)f2bf(a) | ((unsigned)f2bf(b) << 16);
}

// ---------------- prep: W f32 -> bf16 pre-swizzled image --------------------
// image[z]: tile(ks 0..7, nb 0..3) of 16KB at z*512K + ks*64K + nb*16K;
//   byte(col, kb) = col*128 + ((kb^(col&7))<<4), col local (global n = nb*128+col),
//   content = bf16( W[n][ks*64 + kb*8 .. +8) ).   z in {q,k,v,o}.
__global__ __launch_bounds__(256) void prep_kernel(
    const float* __restrict__ Wq, const float* __restrict__ Wk,
    const float* __restrict__ Wv, const float* __restrict__ Wo,
    char* __restrict__ img) {
  int s = blockIdx.x * 256 + threadIdx.x;  // 131072 total 16B chunks
  int z = s >> 15;
  int r = s & 32767;
  int colg = r >> 6;        // 0..511
  int ks = (r >> 3) & 7;
  int kb = r & 7;
  int nb = colg >> 7;
  int col = colg & 127;
  const float* W = (z == 0) ? Wq : (z == 1) ? Wk : (z == 2) ? Wv : Wo;
  const float* src = W + (size_t)colg * 512 + ks * 64 + kb * 8;
  v4f a = *reinterpret_cast<const v4f*>(src);
  v4f c = *reinterpret_cast<const v4f*>(src + 4);
  uint4 hv = make_uint4(pk2(a[0], a[1]), pk2(a[2], a[3]), pk2(c[0], c[1]), pk2(c[2], c[3]));
  *reinterpret_cast<uint4*>(img + (size_t)z * 524288 + ks * 65536 + nb * 16384 +
                            col * 128 + ((kb ^ (col & 7)) << 4)) = hv;
}

// ---------------- projection GEMM: Y = act(X @ W^T + b) -> bf16 -------------
// grid (4 n-blocks, 256 m-blocks, 3 inputs), 256 threads = 4 waves (2M x 2N)
__global__ __launch_bounds__(256) void proj_kernel(
    const float* __restrict__ X0, const float* __restrict__ X1, const float* __restrict__ X2,
    const char* __restrict__ imgBase,
    const float* __restrict__ Bb0, const float* __restrict__ Bb1, const float* __restrict__ Bb2,
    ushort* __restrict__ Y0, ushort* __restrict__ Y1, ushort* __restrict__ Y2) {
  __shared__ char As[128 * 128];  // 16KB
  __shared__ char Bs[128 * 128];  // 16KB
  const int z = blockIdx.z;
  const float* __restrict__ X  = (z == 0) ? X0  : (z == 1) ? X1  : X2;
  const float* __restrict__ Bb = (z == 0) ? Bb0 : (z == 1) ? Bb1 : Bb2;
  ushort* __restrict__ Y       = (z == 0) ? Y0  : (z == 1) ? Y1  : Y2;
  const char* __restrict__ img = imgBase + (size_t)z * 524288 + blockIdx.x * 16384;
  const bool do_elu = (z < 2);

  const int tid = threadIdx.x;
  const int lane = tid & 63;
  const int wv = tid >> 6;
  const int wr = wv >> 1, wc = wv & 1;
  const int n0 = blockIdx.x * 128;
  const int m0 = blockIdx.y * 128;

  const v4f vzero = {0.f, 0.f, 0.f, 0.f};
  v4f acc[4][4];
#pragma unroll
  for (int i = 0; i < 4; ++i)
#pragma unroll
    for (int j = 0; j < 4; ++j) acc[i][j] = vzero;

  for (int ks = 0; ks < 8; ++ks) {
    const int k0 = ks << 6;
    __syncthreads();
    // B tile: async DMA, linear LDS dst (global image is pre-swizzled)
    {
      const char* wsrc = img + (ks << 16) + (wv << 12) + (lane << 4);
      char* bdst = Bs + (wv << 12);  // wave-uniform base; HW adds lane*16
#pragma unroll
      for (int i = 0; i < 4; ++i) glds16(wsrc + i * 1024, bdst + i * 1024);
    }
    // A tile: reg-staged f32 -> bf16, swizzled ds_write_b128
#pragma unroll
    for (int r = 0; r < 4; ++r) {
      int s = tid + (r << 8);
      int row = s >> 3;
      int kb = s & 7;
      const float* src = X + (size_t)(m0 + row) * 512 + k0 + (kb << 3);
      v4f a = *reinterpret_cast<const v4f*>(src);
      v4f c = *reinterpret_cast<const v4f*>(src + 4);
      uint4 hv = make_uint4(pk2(a[0], a[1]), pk2(a[2], a[3]), pk2(c[0], c[1]), pk2(c[2], c[3]));
      *reinterpret_cast<uint4*>(As + (row << 7) + ((kb ^ (row & 7)) << 4)) = hv;
    }
    __syncthreads();

#pragma unroll
    for (int kk = 0; kk < 2; ++kk) {
      const int kb = (kk << 2) + (lane >> 4);
      v8s bfrg[4], afrg[4];
#pragma unroll
      for (int ni = 0; ni < 4; ++ni) {
        int col = (wc << 6) + (ni << 4) + (lane & 15);
        bfrg[ni] = *reinterpret_cast<const v8s*>(Bs + (col << 7) + ((kb ^ (col & 7)) << 4));
      }
#pragma unroll
      for (int mi = 0; mi < 4; ++mi) {
        int row = (wr << 6) + (mi << 4) + (lane & 15);
        afrg[mi] = *reinterpret_cast<const v8s*>(As + (row << 7) + ((kb ^ (row & 7)) << 4));
      }
#pragma unroll
      for (int mi = 0; mi < 4; ++mi)
#pragma unroll
        for (int ni = 0; ni < 4; ++ni)
          acc[mi][ni] = __builtin_amdgcn_mfma_f32_16x16x32_bf16(bfrg[ni], afrg[mi], acc[mi][ni], 0, 0, 0);
    }
  }

  // swapped epilogue: output row = lane&15, output col quad = (lane>>4)*4
#pragma unroll
  for (int ni = 0; ni < 4; ++ni) {
    const int col4 = n0 + (wc << 6) + (ni << 4) + ((lane >> 4) << 2);
    v4f bb = *reinterpret_cast<const v4f*>(Bb + col4);
#pragma unroll
    for (int mi = 0; mi < 4; ++mi) {
      const int row = m0 + (wr << 6) + (mi << 4) + (lane & 15);
      float v0 = acc[mi][ni][0] + bb[0];
      float v1 = acc[mi][ni][1] + bb[1];
      float v2 = acc[mi][ni][2] + bb[2];
      float v3 = acc[mi][ni][3] + bb[3];
      if (do_elu) {
        v0 = (v0 > 0.f) ? (v0 + 1.f) : __expf(v0);
        v1 = (v1 > 0.f) ? (v1 + 1.f) : __expf(v1);
        v2 = (v2 > 0.f) ? (v2 + 1.f) : __expf(v2);
        v3 = (v3 > 0.f) ? (v3 + 1.f) : __expf(v3);
      }
      uint2 o;
      o.x = pk2(v0, v1);
      o.y = pk2(v2, v3);
      *reinterpret_cast<uint2*>(Y + (size_t)row * 512 + col4) = o;
    }
  }
}

// ---------------- ctx[bh][c][d] = sum_t kh*vh ; ksum[bh][c]  (MFMA) ---------
__global__ __launch_bounds__(256) void ctx_kernel(
    const ushort* __restrict__ KH, const ushort* __restrict__ VH,
    float* __restrict__ CTX, float* __restrict__ KSUM) {
  __shared__ char sm[34816];  // klT[64][136us] + vlT[64][136us]; reused as 2x16KB f32
  __shared__ float ksp[256];
  ushort* klT = (ushort*)sm;            // row stride 272 B
  ushort* vlT = (ushort*)(sm + 17408);
  float* red0 = (float*)sm;
  float* red1 = (float*)(sm + 16384);

  const int tid = threadIdx.x;
  const int lane = tid & 63;
  const int wv = tid >> 6;
  const int bh = blockIdx.y;
  const int b = bh >> 3, h = bh & 7;
  const int tbase = blockIdx.x << 10;

  const v4f vzero = {0.f, 0.f, 0.f, 0.f};
  v4f acc[4][4];
#pragma unroll
  for (int i = 0; i < 4; ++i)
#pragma unroll
    for (int j = 0; j < 4; ++j) acc[i][j] = vzero;
  float ks = 0.f;

  const int c8 = (tid & 7) << 3;
  const int tp = (tid >> 3) << 1;  // even t in [0,64)

  for (int it = 0; it < 8; ++it) {
    __syncthreads();
#pragma unroll
    for (int r = 0; r < 2; ++r) {
      int tloc = tp + (r << 6);
      size_t g = ((size_t)(b * 8192 + tbase + (it << 7) + tloc)) * 512 + (h << 6) + c8;
      uint4 ka = *reinterpret_cast<const uint4*>(KH + g);
      uint4 kb = *reinterpret_cast<const uint4*>(KH + g + 512);
      uint4 va = *reinterpret_cast<const uint4*>(VH + g);
      uint4 vb = *reinterpret_cast<const uint4*>(VH + g + 512);
      const ushort* pka = (const ushort*)&ka;
      const ushort* pkb = (const ushort*)&kb;
      const ushort* pva = (const ushort*)&va;
      const ushort* pvb = (const ushort*)&vb;
#pragma unroll
      for (int i = 0; i < 8; ++i) {
        unsigned kw = (unsigned)pka[i] | ((unsigned)pkb[i] << 16);
        unsigned vw = (unsigned)pva[i] | ((unsigned)pvb[i] << 16);
        *reinterpret_cast<unsigned*>((char*)klT + (c8 + i) * 272 + tloc * 2) = kw;
        *reinterpret_cast<unsigned*>((char*)vlT + (c8 + i) * 272 + tloc * 2) = vw;
      }
    }
    __syncthreads();
    const int tw = wv << 5;
    const int ko = (tw + ((lane >> 4) << 3)) << 1;
    v8s af[4], bf_[4];
#pragma unroll
    for (int ci = 0; ci < 4; ++ci)
      af[ci] = *reinterpret_cast<const v8s*>((char*)klT + ((ci << 4) + (lane & 15)) * 272 + ko);
#pragma unroll
    for (int di = 0; di < 4; ++di)
      bf_[di] = *reinterpret_cast<const v8s*>((char*)vlT + ((di << 4) + (lane & 15)) * 272 + ko);
#pragma unroll
    for (int ci = 0; ci < 4; ++ci)
#pragma unroll
      for (int di = 0; di < 4; ++di)
        acc[ci][di] = __builtin_amdgcn_mfma_f32_16x16x32_bf16(af[ci], bf_[di], acc[ci][di], 0, 0, 0);
#pragma unroll
    for (int q = 0; q < 4; ++q) {
      v8s kv = *reinterpret_cast<const v8s*>((char*)klT + lane * 272 + ((tw + (q << 3)) << 1));
#pragma unroll
      for (int i = 0; i < 8; ++i) ks += bf2f((ushort)kv[i]);
    }
  }

  __syncthreads();
  if (wv == 2) {
#pragma unroll
    for (int ci = 0; ci < 4; ++ci)
#pragma unroll
      for (int di = 0; di < 4; ++di)
#pragma unroll
        for (int j = 0; j < 4; ++j)
          red0[((ci << 4) + ((lane >> 4) << 2) + j) * 64 + (di << 4) + (lane & 15)] = acc[ci][di][j];
  }
  if (wv == 3) {
#pragma unroll
    for (int ci = 0; ci < 4; ++ci)
#pragma unroll
      for (int di = 0; di < 4; ++di)
#pragma unroll
        for (int j = 0; j < 4; ++j)
          red1[((ci << 4) + ((lane >> 4) << 2) + j) * 64 + (di << 4) + (lane & 15)] = acc[ci][di][j];
  }
  ksp[tid] = ks;
  __syncthreads();
  if (wv == 0) {
#pragma unroll
    for (int ci = 0; ci < 4; ++ci)
#pragma unroll
      for (int di = 0; di < 4; ++di)
#pragma unroll
        for (int j = 0; j < 4; ++j)
          acc[ci][di][j] += red0[((ci << 4) + ((lane >> 4) << 2) + j) * 64 + (di << 4) + (lane & 15)];
  }
  if (wv == 1) {
#pragma unroll
    for (int ci = 0; ci < 4; ++ci)
#pragma unroll
      for (int di = 0; di < 4; ++di)
#pragma unroll
        for (int j = 0; j < 4; ++j)
          acc[ci][di][j] += red1[((ci << 4) + ((lane >> 4) << 2) + j) * 64 + (di << 4) + (lane & 15)];
  }
  __syncthreads();
  if (wv == 1) {
#pragma unroll
    for (int ci = 0; ci < 4; ++ci)
#pragma unroll
      for (int di = 0; di < 4; ++di)
#pragma unroll
        for (int j = 0; j < 4; ++j)
          red0[((ci << 4) + ((lane >> 4) << 2) + j) * 64 + (di << 4) + (lane & 15)] = acc[ci][di][j];
  }
  __syncthreads();
  if (wv == 0) {
#pragma unroll
    for (int ci = 0; ci < 4; ++ci)
#pragma unroll
      for (int di = 0; di < 4; ++di)
#pragma unroll
        for (int j = 0; j < 4; ++j) {
          int c = (ci << 4) + ((lane >> 4) << 2) + j;
          int d = (di << 4) + (lane & 15);
          float val = acc[ci][di][j] + red0[c * 64 + d];
          atomicAdd(&CTX[(bh << 12) + (c << 6) + d], val);
        }
    float ksv = ksp[lane] + ksp[64 + lane] + ksp[128 + lane] + ksp[192 + lane];
    atomicAdd(&KSUM[(bh << 6) + lane], ksv);
  }
}

// ---------------- o = (qh @ ctx) / (qh . ksum) -> bf16 ----------------------
__global__ __launch_bounds__(256) void numdiv_kernel(
    const ushort* __restrict__ QH, const float* __restrict__ CTX,
    const float* __restrict__ KSUM, ushort* __restrict__ O) {
  __shared__ float ctxl[4096];
  __shared__ float ksl[64];
  __shared__ ushort qtl[64 * 138];
  const int tid = threadIdx.x;
  const int bh = blockIdx.y;
  const int b = bh >> 3, h = bh & 7;
  const int t0 = blockIdx.x << 7;

#pragma unroll
  for (int r = 0; r < 4; ++r) {
    int s = tid + (r << 8);
    int row = s >> 4;
    int c4 = (s & 15) << 2;
    *reinterpret_cast<v4f*>(&ctxl[(row << 6) + c4]) =
        *reinterpret_cast<const v4f*>(&CTX[(bh << 12) + (row << 6) + c4]);
  }
  if (tid < 64) ksl[tid] = KSUM[(bh << 6) + tid];
#pragma unroll
  for (int r = 0; r < 4; ++r) {
    int s = tid + (r << 8);
    int trow = s >> 3;
    int cb = (s & 7) << 3;
    uint4 raw = *reinterpret_cast<const uint4*>(
        QH + ((size_t)(b * 8192 + t0 + trow)) * 512 + (h << 6) + cb);
    const ushort* p = reinterpret_cast<const ushort*>(&raw);
#pragma unroll
    for (int i = 0; i < 8; ++i) qtl[(cb + i) * 138 + trow] = p[i];
  }
  __syncthreads();

  const int l = tid & 63;
  const int dw = (tid >> 6) << 4;
  float a0[16], a1[16];
#pragma unroll
  for (int j = 0; j < 16; ++j) { a0[j] = 0.f; a1[j] = 0.f; }
  float den0 = 0.f, den1 = 0.f;

  for (int c = 0; c < 64; ++c) {
    float q0 = bf2f(qtl[c * 138 + l]);
    float q1 = bf2f(qtl[c * 138 + 64 + l]);
    float kv = ksl[c];
    den0 += q0 * kv;
    den1 += q1 * kv;
#pragma unroll
    for (int p4 = 0; p4 < 4; ++p4) {
      v4f cv = *reinterpret_cast<const v4f*>(&ctxl[(c << 6) + dw + (p4 << 2)]);
#pragma unroll
      for (int jj = 0; jj < 4; ++jj) {
        a0[(p4 << 2) + jj] += q0 * cv[jj];
        a1[(p4 << 2) + jj] += q1 * cv[jj];
      }
    }
  }
  float i0 = 1.f / den0, i1 = 1.f / den1;
  {
    size_t ro = ((size_t)(b * 8192 + t0 + l)) * 512 + (h << 6) + dw;
    uint4 w0 = make_uint4(pk2(a0[0] * i0, a0[1] * i0), pk2(a0[2] * i0, a0[3] * i0),
                          pk2(a0[4] * i0, a0[5] * i0), pk2(a0[6] * i0, a0[7] * i0));
    uint4 w1 = make_uint4(pk2(a0[8] * i0, a0[9] * i0), pk2(a0[10] * i0, a0[11] * i0),
                          pk2(a0[12] * i0, a0[13] * i0), pk2(a0[14] * i0, a0[15] * i0));
    *reinterpret_cast<uint4*>(O + ro) = w0;
    *reinterpret_cast<uint4*>(O + ro + 8) = w1;
  }
  {
    size_t ro = ((size_t)(b * 8192 + t0 + 64 + l)) * 512 + (h << 6) + dw;
    uint4 w0 = make_uint4(pk2(a1[0] * i1, a1[1] * i1), pk2(a1[2] * i1, a1[3] * i1),
                          pk2(a1[4] * i1, a1[5] * i1), pk2(a1[6] * i1, a1[7] * i1));
    uint4 w1 = make_uint4(pk2(a1[8] * i1, a1[9] * i1), pk2(a1[10] * i1, a1[11] * i1),
                          pk2(a1[12] * i1, a1[13] * i1), pk2(a1[14] * i1, a1[15] * i1));
    *reinterpret_cast<uint4*>(O + ro) = w0;
    *reinterpret_cast<uint4*>(O + ro + 8) = w1;
  }
}

// ---------------- out = o @ Wo^T + bo -> f32 --------------------------------
// grid (4 n-blocks, 256 m-blocks), 256 threads = 4 waves. BOTH tiles stream via
// global_load_lds: A's XOR swizzle is applied to the per-lane GLOBAL src addr
// (chunks are 16B within a contiguous 128B k-span of a row), LDS dst linear.
__global__ __launch_bounds__(256) void out_kernel(
    const ushort* __restrict__ O, const char* __restrict__ imgO,
    const float* __restrict__ bo, float* __restrict__ OUT) {
  __shared__ char As[128 * 128];
  __shared__ char Bs[128 * 128];
  const int tid = threadIdx.x;
  const int lane = tid & 63;
  const int wv = tid >> 6;
  const int wr = wv >> 1, wc = wv & 1;
  const int n0 = blockIdx.x * 128;
  const int m0 = blockIdx.y * 128;
  const char* __restrict__ img = imgO + blockIdx.x * 16384;

  const v4f vzero = {0.f, 0.f, 0.f, 0.f};
  v4f acc[4][4];
#pragma unroll
  for (int i = 0; i < 4; ++i)
#pragma unroll
    for (int j = 0; j < 4; ++j) acc[i][j] = vzero;

  for (int ks = 0; ks < 8; ++ks) {
    const int k0 = ks << 6;
    __syncthreads();
    {
      const char* wsrc = img + (ks << 16) + (wv << 12) + (lane << 4);
      char* bdst = Bs + (wv << 12);
#pragma unroll
      for (int i = 0; i < 4; ++i) glds16(wsrc + i * 1024, bdst + i * 1024);
    }
    // A: glds16 with pre-swizzled per-lane global source
#pragma unroll
    for (int r = 0; r < 4; ++r) {
      int c = (wv << 8) + (r << 6) + lane;  // chunk 0..1023
      int row = c >> 3;
      int kb = c & 7;
      int kbs = kb ^ (row & 7);
      const char* src = (const char*)(O + (size_t)(m0 + row) * 512 + k0 + (kbs << 3));
      glds16(src, As + (wv << 12) + (r << 10));
    }
    __syncthreads();

#pragma unroll
    for (int kk = 0; kk < 2; ++kk) {
      const int kb = (kk << 2) + (lane >> 4);
      v8s bfrg[4], afrg[4];
#pragma unroll
      for (int ni = 0; ni < 4; ++ni) {
        int col = (wc << 6) + (ni << 4) + (lane & 15);
        bfrg[ni] = *reinterpret_cast<const v8s*>(Bs + (col << 7) + ((kb ^ (col & 7)) << 4));
      }
#pragma unroll
      for (int mi = 0; mi < 4; ++mi) {
        int row = (wr << 6) + (mi << 4) + (lane & 15);
        afrg[mi] = *reinterpret_cast<const v8s*>(As + (row << 7) + ((kb ^ (row & 7)) << 4));
      }
#pragma unroll
      for (int mi = 0; mi < 4; ++mi)
#pragma unroll
        for (int ni = 0; ni < 4; ++ni)
          acc[mi][ni] = __builtin_amdgcn_mfma_f32_16x16x32_bf16(bfrg[ni], afrg[mi], acc[mi][ni], 0, 0, 0);
    }
  }

#pragma unroll
  for (int ni = 0; ni < 4; ++ni) {
    const int col4 = n0 + (wc << 6) + (ni << 4) + ((lane >> 4) << 2);
    v4f bb = *reinterpret_cast<const v4f*>(bo + col4);
#pragma unroll
    for (int mi = 0; mi < 4; ++mi) {
      const int row = m0 + (wr << 6) + (mi << 4) + (lane & 15);
      v4f st;
      st[0] = acc[mi][ni][0] + bb[0];
      st[1] = acc[mi][ni][1] + bb[1];
      st[2] = acc[mi][ni][2] + bb[2];
      st[3] = acc[mi][ni][3] + bb[3];
      *reinterpret_cast<v4f*>(OUT + (size_t)row * 512 + col4) = st;
    }
  }
}

extern "C" void kernel_launch(void* const* d_in, const int* in_sizes, int n_in,
                              void* d_out, int out_size, void* d_ws, size_t ws_size,
                              hipStream_t stream) {
  const float* q  = (const float*)d_in[0];
  const float* k  = (const float*)d_in[1];
  const float* v  = (const float*)d_in[2];
  const float* Wq = (const float*)d_in[3];
  const float* bq = (const float*)d_in[4];
  const float* Wk = (const float*)d_in[5];
  const float* bk = (const float*)d_in[6];
  const float* Wv = (const float*)d_in[7];
  const float* bv = (const float*)d_in[8];
  const float* Wo = (const float*)d_in[9];
  const float* bo = (const float*)d_in[10];
  float* out = (float*)d_out;

  // ws: qh | kh | vh | ctx(512K) | ksum(8K) | Wimg(2M);  o aliases qh (safe:
  // numdiv stages its exact read region to LDS before overwriting it)
  char* ws = (char*)d_ws;
  const size_t SZ = 33554432ull;
  ushort* qh = (ushort*)(ws);
  ushort* kh = (ushort*)(ws + SZ);
  ushort* vh = (ushort*)(ws + 2 * SZ);
  float* ctx  = (float*)(ws + 3 * SZ);
  float* ksum = (float*)(ws + 3 * SZ + 524288);
  char* wimg  = ws + 3 * SZ + 532480;

  hipMemsetAsync(ws + 3 * SZ, 0, 532480, stream);
  prep_kernel<<<512, 256, 0, stream>>>(Wq, Wk, Wv, Wo, wimg);
  proj_kernel<<<dim3(4, 256, 3), 256, 0, stream>>>(q, k, v, wimg, bq, bk, bv, qh, kh, vh);
  ctx_kernel<<<dim3(8, 32), 256, 0, stream>>>(kh, vh, ctx, ksum);
  numdiv_kernel<<<dim3(64, 32), 256, 0, stream>>>(qh, ctx, ksum, qh);
  out_kernel<<<dim3(4, 256), 256, 0, stream>>>(qh, wimg + 3 * 524288, bo, out);
}